// Round 3
// baseline (192.431 us; speedup 1.0000x reference)
//
#include <hip/hip_runtime.h>
#include <math.h>

namespace {
constexpr int kB     = 64;
constexpr int kH     = 32;
constexpr int kKVH   = 8;
constexpr int kG     = 4;     // H / KVH
constexpr int kD     = 128;
constexpr int kBS    = 128;
constexpr int kNBPS  = 16;
constexpr int kRowF  = kKVH * kD;   // floats per position in cache = 1024
constexpr float kScale = 0.08838834764831845f; // 1/sqrt(128)

typedef float f4 __attribute__((ext_vector_type(4)));
typedef float f2 __attribute__((ext_vector_type(2)));
}

// ---------------- Phase 1: one block per (b, cache_block); wave w owns kvh=w ----
// Reads the cache block's K/V fully contiguously (8 waves cover all kvh strips).
__global__ __launch_bounds__(512)
void pa_partial(const float* __restrict__ q,
                const float* __restrict__ knew,
                const float* __restrict__ vnew,
                const float* __restrict__ kcache,
                const float* __restrict__ vcache,
                const int* __restrict__ block_tables,
                const int* __restrict__ ctx_lens,
                float* __restrict__ m_part,   // [B][KVH][NBPS][G]
                float* __restrict__ l_part,   // [B][KVH][NBPS][G]
                float* __restrict__ o_part)   // [B][KVH][NBPS][G][D]
{
  const int blk = blockIdx.x & (kNBPS - 1);
  const int b   = blockIdx.x >> 4;
  const int ctx = ctx_lens[b];
  const int start = blk * kBS;
  if (start >= ctx) return;
  const int end  = min(kBS, ctx - start);   // local valid position count (>=1)
  const int last = ctx - 1;

  const int tid  = threadIdx.x;
  const int kvh  = tid >> 6;     // wave id = kv head
  const int lane = tid & 63;
  const int grp  = lane >> 5;    // 0: even pos of pair, 1: odd
  const int l32  = lane & 31;

  const int bt = block_tables[b * kNBPS + blk];
  const float* kbase = kcache + (size_t)bt * (kBS * kRowF) + kvh * kD;
  const float* vbase = vcache + (size_t)bt * (kBS * kRowF) + kvh * kD;
  const float* knew_row = knew + (b * kKVH + kvh) * kD;
  const float* vnew_row = vnew + (b * kKVH + kvh) * kD;

  // q fragment: head g, dims [l32*4, l32*4+4)
  f4 qf[kG];
#pragma unroll
  for (int g = 0; g < kG; ++g)
    qf[g] = *reinterpret_cast<const f4*>(q + (b * kH + kvh * kG + g) * kD + l32 * 4);

  float m[kG], l[kG];
  f2 acc[kG];   // lane owns d = lane*2, lane*2+1
#pragma unroll
  for (int g = 0; g < kG; ++g) { m[g] = -INFINITY; l[g] = 0.f; acc[g] = (f2){0.f, 0.f}; }

  const int np = (end + 1) >> 1;   // pairs

  auto kptr = [&](int i) -> const f4* {
    const int pe  = 2 * i;
    const bool ov = (pe + 1) < end;
    const int j   = pe + ((grp && ov) ? 1 : 0);
    const float* r = (start + j == last) ? knew_row : (kbase + (size_t)j * kRowF);
    return reinterpret_cast<const f4*>(r + l32 * 4);
  };
  auto vptr = [&](int j) -> const f2* {
    const float* r = (start + j == last) ? vnew_row : (vbase + (size_t)j * kRowF);
    return reinterpret_cast<const f2*>(r + lane * 2);
  };

  f4 kf = __builtin_nontemporal_load(kptr(0));
  f2 ve = __builtin_nontemporal_load(vptr(0));
  f2 vo = __builtin_nontemporal_load(vptr((1 < end) ? 1 : 0));

  for (int i = 0; i < np; ++i) {
    const int pe  = 2 * i;
    const bool ov = (pe + 1) < end;
    const bool myvalid = (!grp) || ov;

    // prefetch next pair
    f4 nkf; f2 nve, nvo;
    if (i + 1 < np) {
      const int npe  = 2 * (i + 1);
      const bool nov = (npe + 1) < end;
      nkf = __builtin_nontemporal_load(kptr(i + 1));
      nve = __builtin_nontemporal_load(vptr(npe));
      nvo = __builtin_nontemporal_load(vptr(nov ? npe + 1 : npe));
    }

    // ---- 4-head dot products, reduced over the 32-lane group ----
    float s[kG];
#pragma unroll
    for (int g = 0; g < kG; ++g) {
      s[g] = qf[g].x * kf.x;
      s[g] = fmaf(qf[g].y, kf.y, s[g]);
      s[g] = fmaf(qf[g].z, kf.z, s[g]);
      s[g] = fmaf(qf[g].w, kf.w, s[g]);
    }
#pragma unroll
    for (int off = 1; off < 32; off <<= 1) {
#pragma unroll
      for (int g = 0; g < kG; ++g) s[g] += __shfl_xor(s[g], off);
    }
#pragma unroll
    for (int g = 0; g < kG; ++g)
      s[g] = myvalid ? s[g] * kScale : -INFINITY;

    // exchange across the 32-boundary: all lanes get both positions' scores
    float se[kG], so[kG];
#pragma unroll
    for (int g = 0; g < kG; ++g) {
      const float s2 = __shfl_xor(s[g], 32);
      se[g] = grp ? s2   : s[g];
      so[g] = grp ? s[g] : s2;
    }

    // ---- online softmax + V accumulation ----
#pragma unroll
    for (int g = 0; g < kG; ++g) {
      const float pm = fmaxf(se[g], so[g]);
      if (pm > m[g]) {                        // wave-uniform
        const float cf = __expf(m[g] - pm);
        m[g] = pm;
        l[g] *= cf;
        acc[g].x *= cf;
        acc[g].y *= cf;
      }
      const float ee = __expf(se[g] - m[g]);
      const float eo = __expf(so[g] - m[g]);  // 0 if odd invalid
      l[g] += ee + eo;
      acc[g].x = fmaf(ee, ve.x, fmaf(eo, vo.x, acc[g].x));
      acc[g].y = fmaf(ee, ve.y, fmaf(eo, vo.y, acc[g].y));
    }

    kf = nkf; ve = nve; vo = nvo;
  }

  // ---- write per-(b,kvh,blk,g) partials (no cross-wave reduction needed) ----
  const size_t base = (((size_t)(b * kKVH + kvh)) * kNBPS + blk) * kG;
#pragma unroll
  for (int g = 0; g < kG; ++g) {
    o_part[(base + g) * kD + lane * 2]     = acc[g].x;
    o_part[(base + g) * kD + lane * 2 + 1] = acc[g].y;
  }
  if (lane == 0) {
#pragma unroll
    for (int g = 0; g < kG; ++g) { m_part[base + g] = m[g]; l_part[base + g] = l[g]; }
  }
}

// ---------------- Phase 2: combine splits ----------------
__global__ __launch_bounds__(512)
void pa_reduce(const float* __restrict__ m_part,
               const float* __restrict__ l_part,
               const float* __restrict__ o_part,
               const int* __restrict__ ctx_lens,
               float* __restrict__ out)
{
  const int job = blockIdx.x;     // b*KVH + kvh
  const int b   = job >> 3;
  const int kvh = job & 7;
  const int tid = threadIdx.x;
  const int g   = tid >> 7;       // 512 threads: 4 heads x 128 dims
  const int d   = tid & 127;
  const int ctx  = ctx_lens[b];
  const int nact = (ctx + kBS - 1) >> 7;

  const size_t base = (size_t)job * kNBPS * kG + g;
  float M = -INFINITY;
  for (int s = 0; s < nact; ++s) M = fmaxf(M, m_part[base + (size_t)s * kG]);
  float L = 0.f, o = 0.f;
  for (int s = 0; s < nact; ++s) {
    const size_t idx = base + (size_t)s * kG;
    const float f = __expf(m_part[idx] - M);
    L = fmaf(f, l_part[idx], L);
    o = fmaf(f, o_part[idx * kD + d], o);
  }
  out[((b * kH) + kvh * kG + g) * kD + d] = o / L;
}

// ---------------- Fallback: round-1 single kernel (if ws too small) ----------------
__global__ __launch_bounds__(512, 4)
void pa_decode_kernel(const float* __restrict__ q,
                      const float* __restrict__ knew,
                      const float* __restrict__ vnew,
                      const float* __restrict__ kcache,
                      const float* __restrict__ vcache,
                      const int* __restrict__ block_tables,
                      const int* __restrict__ ctx_lens,
                      float* __restrict__ out)
{
  const int job  = blockIdx.x;
  const int b    = job >> 3;
  const int kvh  = job & 7;
  const int tid  = threadIdx.x;
  const int wave = tid >> 6;
  const int lane = tid & 63;
  const int grp  = lane >> 5;
  const int l32  = lane & 31;

  __shared__ int   bt[kNBPS];
  __shared__ float red_m[8][kG];
  __shared__ float red_l[8][kG];
  __shared__ float red_acc[8][kG][kD];

  if (tid < kNBPS) bt[tid] = block_tables[b * kNBPS + tid];
  const int ctx = ctx_lens[b];
  __syncthreads();

  float4 qf[kG];
#pragma unroll
  for (int g = 0; g < kG; ++g)
    qf[g] = *reinterpret_cast<const float4*>(q + (b * kH + kvh * kG + g) * kD + l32 * 4);

  float  m[kG], l[kG];
  float2 acc[kG];
#pragma unroll
  for (int g = 0; g < kG; ++g) { m[g] = -INFINITY; l[g] = 0.f; acc[g] = make_float2(0.f, 0.f); }

  const float* knew_row = knew + (b * kKVH + kvh) * kD;
  const float* vnew_row = vnew + (b * kKVH + kvh) * kD;
  const int last   = ctx - 1;
  const int npairs = (ctx + 1) >> 1;

  for (int pair = wave; pair < npairs; pair += 8) {
    const int  pe      = pair * 2;
    const bool ovalid  = (pe + 1) < ctx;
    const int  myp     = (grp && ovalid) ? (pe + 1) : pe;
    const bool myvalid = (!grp) || ovalid;

    const float* krow = (myp == last) ? knew_row
        : kcache + ((size_t)(bt[myp >> 7] * kBS + (myp & 127)) * kKVH + kvh) * kD;
    const float4 kf = *reinterpret_cast<const float4*>(krow + l32 * 4);

    const int poc = ovalid ? (pe + 1) : pe;
    const float* vrow_e = (pe == last) ? vnew_row
        : vcache + ((size_t)(bt[pe >> 7] * kBS + (pe & 127)) * kKVH + kvh) * kD;
    const float* vrow_o = (poc == last) ? vnew_row
        : vcache + ((size_t)(bt[poc >> 7] * kBS + (poc & 127)) * kKVH + kvh) * kD;
    const float2 ve = *reinterpret_cast<const float2*>(vrow_e + lane * 2);
    const float2 vo = *reinterpret_cast<const float2*>(vrow_o + lane * 2);

    float s[kG];
#pragma unroll
    for (int g = 0; g < kG; ++g) {
      s[g] = qf[g].x * kf.x;
      s[g] = fmaf(qf[g].y, kf.y, s[g]);
      s[g] = fmaf(qf[g].z, kf.z, s[g]);
      s[g] = fmaf(qf[g].w, kf.w, s[g]);
    }
#pragma unroll
    for (int off = 1; off < 32; off <<= 1) {
#pragma unroll
      for (int g = 0; g < kG; ++g) s[g] += __shfl_xor(s[g], off);
    }
#pragma unroll
    for (int g = 0; g < kG; ++g)
      s[g] = myvalid ? s[g] * kScale : -INFINITY;

    float se[kG], so[kG];
#pragma unroll
    for (int g = 0; g < kG; ++g) {
      const float s2 = __shfl_xor(s[g], 32);
      se[g] = grp ? s2   : s[g];
      so[g] = grp ? s[g] : s2;
    }

#pragma unroll
    for (int g = 0; g < kG; ++g) {
      const float pm = fmaxf(se[g], so[g]);
      if (pm > m[g]) {
        const float cf = __expf(m[g] - pm);
        m[g] = pm;
        l[g] *= cf;
        acc[g].x *= cf;
        acc[g].y *= cf;
      }
      const float ee = __expf(se[g] - m[g]);
      const float eo = __expf(so[g] - m[g]);
      l[g] += ee + eo;
      acc[g].x = fmaf(ee, ve.x, fmaf(eo, vo.x, acc[g].x));
      acc[g].y = fmaf(ee, ve.y, fmaf(eo, vo.y, acc[g].y));
    }
  }

  if (lane == 0) {
#pragma unroll
    for (int g = 0; g < kG; ++g) { red_m[wave][g] = m[g]; red_l[wave][g] = l[g]; }
  }
#pragma unroll
  for (int g = 0; g < kG; ++g) {
    red_acc[wave][g][lane * 2]     = acc[g].x;
    red_acc[wave][g][lane * 2 + 1] = acc[g].y;
  }
  __syncthreads();

  const int g = tid >> 7;
  const int d = tid & 127;
  float M = -INFINITY;
#pragma unroll
  for (int w = 0; w < 8; ++w) M = fmaxf(M, red_m[w][g]);
  float L = 0.f, o = 0.f;
#pragma unroll
  for (int w = 0; w < 8; ++w) {
    const float f = __expf(red_m[w][g] - M);
    L = fmaf(f, red_l[w][g], L);
    o = fmaf(f, red_acc[w][g][d], o);
  }
  out[(b * kH + kvh * kG + g) * kD + d] = o / L;
}

extern "C" void kernel_launch(void* const* d_in, const int* in_sizes, int n_in,
                              void* d_out, int out_size, void* d_ws, size_t ws_size,
                              hipStream_t stream) {
  const float* q  = (const float*)d_in[0];
  const float* k  = (const float*)d_in[1];
  const float* v  = (const float*)d_in[2];
  const float* kc = (const float*)d_in[3];
  const float* vc = (const float*)d_in[4];
  // d_in[5] = slot_mapping (derivable; unused)
  const int* block_tables = (const int*)d_in[6];
  const int* ctx_lens     = (const int*)d_in[7];
  float* out = (float*)d_out;

  const size_t npart = (size_t)kB * kKVH * kNBPS * kG;              // 32768
  const size_t need  = (npart * 2 + npart * kD) * sizeof(float);    // ~17 MB
  if (ws_size >= need) {
    float* m_part = (float*)d_ws;
    float* l_part = m_part + npart;
    float* o_part = l_part + npart;
    pa_partial<<<kB * kNBPS, 512, 0, stream>>>(
        q, k, v, kc, vc, block_tables, ctx_lens, m_part, l_part, o_part);
    pa_reduce<<<kB * kKVH, 512, 0, stream>>>(m_part, l_part, o_part, ctx_lens, out);
  } else {
    pa_decode_kernel<<<kB * kKVH, 512, 0, stream>>>(q, k, v, kc, vc,
                                                    block_tables, ctx_lens, out);
  }
}